// Round 4
// baseline (358.404 us; speedup 1.0000x reference)
//
#include <hip/hip_runtime.h>
#include <hip/hip_bf16.h>

#define NEG_INF_F (-4294967295.0f)  // -(2^32)+1, matches reference padding

typedef __attribute__((ext_vector_type(8))) short bf16x8;   // MFMA A/B frag (4 VGPRs)
typedef __attribute__((ext_vector_type(4))) float f32x4;    // MFMA C/D frag

__device__ __forceinline__ unsigned short f2bf(float x) {
    unsigned u = __float_as_uint(x);
    return (unsigned short)((u + 0x7fffu + ((u >> 16) & 1u)) >> 16);  // RNE
}
__device__ __forceinline__ unsigned f2bf2(float a, float b) {
    __hip_bfloat162 h2 = __float22bfloat162_rn(make_float2(a, b));
    unsigned r; __builtin_memcpy(&r, &h2, 4); return r;
}
__device__ __forceinline__ float bf2f(unsigned short s) {
    return __uint_as_float(((unsigned)s) << 16);
}

// LDS layout. K uses a 16B-granule XOR swizzle (granule g stored at g^(t&15)) so
// A-fragment ds_read_b128 avoids bank conflicts. h1s[0..3] doubles as the
// cooperative M-build staging buffer (64x64 bf16, granule-swizzled by n&7).
// 73,408 B total -> 2 blocks/CU (146 KB of 160 KB), 16 waves/CU.
struct __align__(16) Smem {
    unsigned short K[200 * 128];     // 51200 B  bf16 keys[b], swizzled
    unsigned short h1s[8][16 * 64];  // 16384 B  M-build buf / per-wave h1 scratch
    float q[128];                    //   512 B
    float maskf[208];                //   832 B
    float cpart[512];                //  2048 B  8 partials of c[n]=q@(W1q+W1d)+b1
    float s[208];                    //   832 B  scores -> softmax weights * (1/200)
    float ppart[384];                //  1536 B  phase-4 quarter partials
    float red[16];                   //    64 B
};
static_assert(sizeof(Smem) <= 80 * 1024, "LDS over 80 KiB (need 2 blocks/CU)");

// NOTE: second __launch_bounds__ arg behaves as CUDA min-BLOCKS-per-CU on this
// toolchain (R3 evidence: (512,4) -> 64 VGPR cap -> 95 MB scratch spills).
// (512,2): 2 blocks * 8 waves = 16 waves/CU -> VGPR cap 128, no spill.
__global__ __launch_bounds__(512, 2)
void attn_fused(const float* __restrict__ Q,    // [2048,128]
                const float* __restrict__ Kg,   // [2048,200,128]
                const int*   __restrict__ kid,  // [2048,200]
                const float* __restrict__ W1,   // [512,64]
                const float* __restrict__ b1,   // [64]
                const float* __restrict__ W2,   // [64,32]
                const float* __restrict__ b2,   // [32]
                const float* __restrict__ W3,   // [32,1]
                const float* __restrict__ b3,   // [1]
                float* __restrict__ out)        // [2048,128]
{
    __shared__ Smem sm;
    const int b    = blockIdx.x;
    const int tid  = threadIdx.x;
    const int wave = tid >> 6;
    const int lane = tid & 63;
    const int l15  = lane & 15;
    const int quad = lane >> 4;

    // Issue q/mask loads early so their latency overlaps staging.
    const float qv = (tid < 128) ? Q[b * 128 + tid] : 0.0f;
    const int   kv = (tid < 200) ? kid[b * 200 + tid] : 0;

    // ---------------- stage keys[b] -> LDS bf16 (swizzled) ----------------
    {
        const float4* src = reinterpret_cast<const float4*>(Kg + (size_t)b * 200 * 128);
        #pragma unroll
        for (int r = 0; r < 13; ++r) {
            const int idx4 = tid + 512 * r;        // 6400 float4 total
            if (r == 12 && tid >= 256) break;      // tail: only 256 remain
            const float4 v = src[idx4];
            const int t = idx4 >> 5;               // 32 float4 per row
            const int e = (idx4 & 31) << 2;
            const int g = (e >> 3) ^ (t & 15);     // granule swizzle
            uint2 pk;
            pk.x = f2bf2(v.x, v.y);
            pk.y = f2bf2(v.z, v.w);
            *reinterpret_cast<uint2*>(&sm.K[t * 128 + g * 8 + (e & 7)]) = pk;
        }
    }
    if (tid < 128) sm.q[tid] = qv;
    if (tid < 200) sm.maskf[tid] = (kv != 0) ? 1.0f : 0.0f;
    __syncthreads();

    // ---------------- small weights into regs (overlaps M build) ----------------
    bf16x8 W2f[2][2];  // B-frags of W2 [64,32]: lane(n=l15, k=quad*8+j)
    #pragma unroll
    for (int ks = 0; ks < 2; ++ks) {
        #pragma unroll
        for (int nt = 0; nt < 2; ++nt) {
            const int n = nt * 16 + l15;
            const int kb = ks * 32 + quad * 8;
            bf16x8 f;
            #pragma unroll
            for (int j = 0; j < 8; ++j) f[j] = (short)f2bf(W2[(kb + j) * 32 + n]);
            W2f[ks][nt] = f;
        }
    }
    const float w3a = W3[l15],  w3b = W3[16 + l15];
    const float b2a = b2[l15],  b2b = b2[16 + l15];
    const float b3v = b3[0];

    // ---------------- c[n] partials: wave w does k-chunk w (16 k's) ------------
    {
        const int n = tid & 63, kc = tid >> 6;
        float acc = (kc == 0) ? b1[n] : 0.0f;
        #pragma unroll 4
        for (int i = 0; i < 16; ++i) {
            const int k = kc * 16 + i;
            acc += sm.q[k] * (W1[k * 64 + n] + W1[(256 + k) * 64 + n]);
        }
        sm.cpart[kc * 64 + n] = acc;
    }

    // ---------------- cooperative M build, two 64-k halves ----------------------
    // M_b[k][n] = (W1k - W1d)[k][n] + q[k]*W1p[k][n], stored transposed Mt[n][k']
    // (bf16, 16B-granule swizzle g^(n&7)), then read out as B-fragments:
    // lane(n=l15, k=quad*8+j).
    bf16x8 Mf[4][4];  // [kstep][ntile]
    {
        unsigned short* Mbuf = &sm.h1s[0][0];      // 4096 shorts = h1s[0..3]
        const int n  = tid & 63;
        const int w8 = (tid >> 6) * 8;             // wave's 8 k' rows
        #pragma unroll
        for (int hf = 0; hf < 2; ++hf) {
            #pragma unroll
            for (int j = 0; j < 8; j += 2) {
                const int kp = w8 + j;             // k' in [0,64)
                const int k  = hf * 64 + kp;
                const float v0 = (W1[(128 + k) * 64 + n] - W1[(256 + k) * 64 + n])
                               + sm.q[k] * W1[(384 + k) * 64 + n];
                const float v1 = (W1[(129 + k) * 64 + n] - W1[(257 + k) * 64 + n])
                               + sm.q[k + 1] * W1[(385 + k) * 64 + n];
                const int g = (kp >> 3) ^ (n & 7);
                *reinterpret_cast<unsigned*>(&Mbuf[n * 64 + g * 8 + (kp & 7)]) = f2bf2(v0, v1);
            }
            __syncthreads();
            #pragma unroll
            for (int ksl = 0; ksl < 2; ++ksl) {
                #pragma unroll
                for (int nt = 0; nt < 4; ++nt) {
                    const int nn = nt * 16 + l15;
                    const int g  = (ksl * 4 + quad) ^ (nn & 7);
                    Mf[hf * 2 + ksl][nt] = *reinterpret_cast<const bf16x8*>(&Mbuf[nn * 64 + g * 8]);
                }
            }
            __syncthreads();
        }
    }
    float cn[4];
    #pragma unroll
    for (int nt = 0; nt < 4; ++nt) {
        const int n = nt * 16 + l15;
        float a = 0.f;
        #pragma unroll
        for (int kc = 0; kc < 8; ++kc) a += sm.cpart[kc * 64 + n];
        cn[nt] = a;
    }

    unsigned short* h1w = &sm.h1s[wave][0];
    const f32x4 zero4 = {0.f, 0.f, 0.f, 0.f};

    // ---------------- tile loop: waves independent ----------------
    // wave w owns tile w (and w+8 for w<5). Tile 12 rows 200..207 read garbage
    // past K[] -- row-contained through both MFMAs, scores forced -inf.
    for (int tile = wave; tile < 13; tile += 8) {
        const int t0 = tile * 16;
        const int t  = t0 + l15;                  // A-frag row for this lane
        f32x4 acc[4] = {zero4, zero4, zero4, zero4};
        #pragma unroll
        for (int ks = 0; ks < 4; ++ks) {
            const int g = (ks * 4 + quad) ^ (t & 15);
            const bf16x8 A = *reinterpret_cast<const bf16x8*>(&sm.K[t * 128 + g * 8]);
            #pragma unroll
            for (int nt = 0; nt < 4; ++nt)
                acc[nt] = __builtin_amdgcn_mfma_f32_16x16x32_bf16(A, Mf[ks][nt], acc[nt], 0, 0, 0);
        }
        // epilogue: + c[n], relu, bf16 -> wave-private scratch in A-layout order
        #pragma unroll
        for (int nt = 0; nt < 4; ++nt) {
            const int n = nt * 16 + l15;
            #pragma unroll
            for (int r = 0; r < 4; ++r) {
                const int m = quad * 4 + r;       // C-layout row
                const float h = fmaxf(acc[nt][r] + cn[nt], 0.0f);
                const int g = (n >> 3) ^ (m & 7);
                h1w[m * 64 + g * 8 + (n & 7)] = f2bf(h);
            }
        }
        // layer 2: [16,64] @ [64,32]
        f32x4 p0 = zero4, p1 = zero4;
        #pragma unroll
        for (int ks = 0; ks < 2; ++ks) {
            const int g = (ks * 4 + quad) ^ (l15 & 7);
            const bf16x8 A2 = *reinterpret_cast<const bf16x8*>(&h1w[l15 * 64 + g * 8]);
            p0 = __builtin_amdgcn_mfma_f32_16x16x32_bf16(A2, W2f[ks][0], p0, 0, 0, 0);
            p1 = __builtin_amdgcn_mfma_f32_16x16x32_bf16(A2, W2f[ks][1], p1, 0, 0, 0);
        }
        // layer 3: relu + dot(W3) in fp32, reduce across the 16 lanes of each quad
        float sv[4];
        #pragma unroll
        for (int r = 0; r < 4; ++r)
            sv[r] = fmaxf(p0[r] + b2a, 0.f) * w3a + fmaxf(p1[r] + b2b, 0.f) * w3b;
        #pragma unroll
        for (int off = 1; off < 16; off <<= 1) {
            #pragma unroll
            for (int r = 0; r < 4; ++r) sv[r] += __shfl_xor(sv[r], off);
        }
        if (l15 == 0) {
            #pragma unroll
            for (int r = 0; r < 4; ++r) {
                const int tt = t0 + quad * 4 + r;
                if (tt < 200)
                    sm.s[tt] = (sm.maskf[tt] != 0.0f) ? (sv[r] + b3v) : NEG_INF_F;
                else if (tt < 208)
                    sm.s[tt] = -__builtin_inff();
            }
        }
    }
    __syncthreads();

    // ---------------- masked softmax over t, fold in 1/200 ----------------
    {
        const float v = (tid < 208) ? sm.s[tid] : -__builtin_inff();
        float m = v;
        #pragma unroll
        for (int off = 32; off >= 1; off >>= 1) m = fmaxf(m, __shfl_xor(m, off));
        if (lane == 0) sm.red[wave] = m;
        __syncthreads();
        m = sm.red[0];
        #pragma unroll
        for (int w = 1; w < 8; ++w) m = fmaxf(m, sm.red[w]);
        const float ev = (tid < 208) ? __expf(v - m) : 0.0f;
        float ssum = ev;
        #pragma unroll
        for (int off = 32; off >= 1; off >>= 1) ssum += __shfl_xor(ssum, off);
        if (lane == 0) sm.red[8 + wave] = ssum;
        __syncthreads();
        float S = sm.red[8];
        #pragma unroll
        for (int w = 1; w < 8; ++w) S += sm.red[8 + w];
        const float inv = 1.0f / (S * 200.0f);   // softmax normalize + mean(/T)
        if (tid < 208) sm.s[tid] = ev * inv;
    }
    __syncthreads();

    // ---------------- out[e] = sum_t w[t] * K[t][e], t-quarters + ILP ---------
    {
        const int e   = tid & 127;
        const int qtr = tid >> 7;                // 0..3, 50 t each
        const int e3  = e & 7;
        const int eh  = e >> 3;
        const int tb0 = qtr * 50;
        float a0 = 0.f, a1 = 0.f, a2 = 0.f, a3 = 0.f;
        #pragma unroll
        for (int i = 0; i < 12; ++i) {
            const int tb = tb0 + i * 4;
            a0 += sm.s[tb + 0] * bf2f(sm.K[(tb + 0) * 128 + ((eh ^ ((tb + 0) & 15)) * 8) + e3]);
            a1 += sm.s[tb + 1] * bf2f(sm.K[(tb + 1) * 128 + ((eh ^ ((tb + 1) & 15)) * 8) + e3]);
            a2 += sm.s[tb + 2] * bf2f(sm.K[(tb + 2) * 128 + ((eh ^ ((tb + 2) & 15)) * 8) + e3]);
            a3 += sm.s[tb + 3] * bf2f(sm.K[(tb + 3) * 128 + ((eh ^ ((tb + 3) & 15)) * 8) + e3]);
        }
        const int tb = tb0 + 48;
        a0 += sm.s[tb + 0] * bf2f(sm.K[(tb + 0) * 128 + ((eh ^ ((tb + 0) & 15)) * 8) + e3]);
        a1 += sm.s[tb + 1] * bf2f(sm.K[(tb + 1) * 128 + ((eh ^ ((tb + 1) & 15)) * 8) + e3]);
        const float acc2 = (a0 + a1) + (a2 + a3);
        if (qtr != 0) sm.ppart[(qtr - 1) * 128 + e] = acc2;
        __syncthreads();
        if (qtr == 0)
            out[(size_t)b * 128 + e] = acc2 + sm.ppart[e] + sm.ppart[128 + e] + sm.ppart[256 + e];
    }
}

extern "C" void kernel_launch(void* const* d_in, const int* in_sizes, int n_in,
                              void* d_out, int out_size, void* d_ws, size_t ws_size,
                              hipStream_t stream) {
    (void)in_sizes; (void)n_in; (void)out_size; (void)d_ws; (void)ws_size;
    attn_fused<<<dim3(2048), dim3(512), 0, stream>>>(
        (const float*)d_in[0], (const float*)d_in[1], (const int*)d_in[2],
        (const float*)d_in[3], (const float*)d_in[4], (const float*)d_in[5],
        (const float*)d_in[6], (const float*)d_in[7], (const float*)d_in[8],
        (float*)d_out);
}

// Round 5
// 346.765 us; speedup vs baseline: 1.0336x; 1.0336x over previous
//
#include <hip/hip_runtime.h>
#include <hip/hip_bf16.h>

#define NEG_INF_F (-4294967295.0f)  // -(2^32)+1, matches reference padding

typedef __attribute__((ext_vector_type(8))) short bf16x8;   // MFMA A/B frag (4 VGPRs)
typedef __attribute__((ext_vector_type(4))) float f32x4;    // MFMA C/D frag

__device__ __forceinline__ unsigned short f2bf(float x) {
    unsigned u = __float_as_uint(x);
    return (unsigned short)((u + 0x7fffu + ((u >> 16) & 1u)) >> 16);  // RNE
}
__device__ __forceinline__ unsigned f2bf2(float a, float b) {
    __hip_bfloat162 h2 = __float22bfloat162_rn(make_float2(a, b));
    unsigned r; __builtin_memcpy(&r, &h2, 4); return r;
}

union FragU { unsigned u[4]; bf16x8 h; };

// Wave-per-b design: ONE barrier total. LDS 47,360 B (2 blocks/CU is plenty —
// grid 512 gives 2 resident anyway; waves are fully independent after setup).
struct __align__(16) Smem {
    unsigned short Wt[2][64 * 128]; // 32768 B  Wc^T / Wp^T bf16, [n][k] swizzled
    unsigned short h1s[4][16 * 64]; //  8192 B  per-wave h1 C->A scratch (R2 layout)
    float q[4][128];                //  2048 B  per-wave q_b
    float c[4][64];                 //  1024 B  per-wave c[n]
    float w[4][208];                //  3328 B  per-wave scores -> weights*(1/200)
};

__global__ __launch_bounds__(256, 2)   // 2 blocks min (CUDA semantics) -> 256 VGPR cap
void attn_fused(const float* __restrict__ Q,    // [2048,128]
                const float* __restrict__ Kg,   // [2048,200,128]
                const int*   __restrict__ kid,  // [2048,200]
                const float* __restrict__ W1,   // [512,64]
                const float* __restrict__ b1,   // [64]
                const float* __restrict__ W2,   // [64,32]
                const float* __restrict__ b2,   // [32]
                const float* __restrict__ W3,   // [32,1]
                const float* __restrict__ b3,   // [1]
                float* __restrict__ out)        // [2048,128]
{
    __shared__ Smem sm;
    const int tid  = threadIdx.x;
    const int wave = tid >> 6;
    const int lane = tid & 63;
    const int l15  = lane & 15;
    const int quad = lane >> 4;
    const int b    = blockIdx.x * 4 + wave;      // this wave's batch element

    // ---- one-time cooperative staging: Wc^T = (W1k - W1d)^T, Wp^T = W1p^T ----
    // bf16, [n][k], 16B-granule swizzle g = (k>>3) ^ (n&15).
    {
        const int n  = tid & 63;
        const int ko = tid >> 6;
        #pragma unroll 8
        for (int i = 0; i < 32; ++i) {
            const int k = i * 4 + ko;
            const float a = W1[(128 + k) * 64 + n];
            const float d = W1[(256 + k) * 64 + n];
            const float p = W1[(384 + k) * 64 + n];
            const int g = (k >> 3) ^ (n & 15);
            sm.Wt[0][n * 128 + g * 8 + (k & 7)] = f2bf(a - d);
            sm.Wt[1][n * 128 + g * 8 + (k & 7)] = f2bf(p);
        }
    }
    // per-wave q staging (wave-local; barrier below also covers it)
    sm.q[wave][lane]      = Q[b * 128 + lane];
    sm.q[wave][64 + lane] = Q[b * 128 + 64 + lane];
    __syncthreads();   // the ONLY block-wide barrier

    // ---- per-wave: c[n] = b1[n] + q @ (W1q + W1d), lane n does one n ----
    {
        const int n = lane;
        float acc = b1[n];
        #pragma unroll 4
        for (int k = 0; k < 128; ++k)
            acc += sm.q[wave][k] * (W1[k * 64 + n] + W1[(256 + k) * 64 + n]);
        sm.c[wave][n] = acc;
    }

    // ---- B-fragments of Wc / Wp from LDS (block-invariant) ----
    bf16x8 Wcf[4][4], Wpf[4][4];   // [ks][nt], lane(n=nt*16+l15, k=ks*32+quad*8+j)
    #pragma unroll
    for (int ks = 0; ks < 4; ++ks) {
        #pragma unroll
        for (int nt = 0; nt < 4; ++nt) {
            const int n = nt * 16 + l15;
            const int g = (ks * 4 + quad) ^ l15;
            Wcf[ks][nt] = *reinterpret_cast<const bf16x8*>(&sm.Wt[0][n * 128 + g * 8]);
            Wpf[ks][nt] = *reinterpret_cast<const bf16x8*>(&sm.Wt[1][n * 128 + g * 8]);
        }
    }
    // W2 B-frags + layer-3 constants (L2-hot scalar loads)
    bf16x8 W2f[2][2];
    #pragma unroll
    for (int ks = 0; ks < 2; ++ks) {
        #pragma unroll
        for (int nt = 0; nt < 2; ++nt) {
            const int n = nt * 16 + l15;
            const int kb = ks * 32 + quad * 8;
            bf16x8 f;
            #pragma unroll
            for (int j = 0; j < 8; ++j) f[j] = (short)f2bf(W2[(kb + j) * 32 + n]);
            W2f[ks][nt] = f;
        }
    }
    const float w3a = W3[l15],  w3b = W3[16 + l15];
    const float b2a = b2[l15],  b2b = b2[16 + l15];
    const float b3v = b3[0];
    // this lane's q chunks (fp32, one 8-float chunk per ks) and c values
    float4 qa[4], qb[4];
    #pragma unroll
    for (int ks = 0; ks < 4; ++ks) {
        const int e0 = ks * 32 + quad * 8;
        qa[ks] = *reinterpret_cast<const float4*>(&sm.q[wave][e0]);
        qb[ks] = *reinterpret_cast<const float4*>(&sm.q[wave][e0 + 4]);
    }
    float cn[4];
    #pragma unroll
    for (int nt = 0; nt < 4; ++nt) cn[nt] = sm.c[wave][nt * 16 + l15];

    unsigned short* h1w = &sm.h1s[wave][0];
    const f32x4 zero4 = {0.f, 0.f, 0.f, 0.f};
    const float* kbase = Kg + (size_t)b * 25600;

    // ---- tile loop: 13 x 16 t-rows, K A-frags straight from HBM/L3 ----
    for (int tile = 0; tile < 13; ++tile) {
        const int t0 = tile * 16;
        const int tr = min(t0 + l15, 199);        // clamp OOB rows (tile 12)
        const float* kr = kbase + tr * 128;
        f32x4 acc[4] = {zero4, zero4, zero4, zero4};
        #pragma unroll
        for (int ks = 0; ks < 4; ++ks) {
            const float4 k0 = *reinterpret_cast<const float4*>(kr + ks * 32 + quad * 8);
            const float4 k1 = *reinterpret_cast<const float4*>(kr + ks * 32 + quad * 8 + 4);
            FragU A1, A2;
            A1.u[0] = f2bf2(k0.x, k0.y);           A1.u[1] = f2bf2(k0.z, k0.w);
            A1.u[2] = f2bf2(k1.x, k1.y);           A1.u[3] = f2bf2(k1.z, k1.w);
            A2.u[0] = f2bf2(k0.x * qa[ks].x, k0.y * qa[ks].y);
            A2.u[1] = f2bf2(k0.z * qa[ks].z, k0.w * qa[ks].w);
            A2.u[2] = f2bf2(k1.x * qb[ks].x, k1.y * qb[ks].y);
            A2.u[3] = f2bf2(k1.z * qb[ks].z, k1.w * qb[ks].w);
            #pragma unroll
            for (int nt = 0; nt < 4; ++nt) {
                acc[nt] = __builtin_amdgcn_mfma_f32_16x16x32_bf16(A1.h, Wcf[ks][nt], acc[nt], 0, 0, 0);
                acc[nt] = __builtin_amdgcn_mfma_f32_16x16x32_bf16(A2.h, Wpf[ks][nt], acc[nt], 0, 0, 0);
            }
        }
        // epilogue: + c[n], relu, bf16 -> wave-private scratch in A-layout (R2 code)
        #pragma unroll
        for (int nt = 0; nt < 4; ++nt) {
            const int n = nt * 16 + l15;
            #pragma unroll
            for (int r = 0; r < 4; ++r) {
                const int m = quad * 4 + r;
                const float h = fmaxf(acc[nt][r] + cn[nt], 0.0f);
                const int g = (n >> 3) ^ (m & 7);
                h1w[m * 64 + g * 8 + (n & 7)] = f2bf(h);
            }
        }
        // layer 2: [16,64] @ [64,32]  (R2 code, wave-local LDS)
        f32x4 p0 = zero4, p1 = zero4;
        #pragma unroll
        for (int ks = 0; ks < 2; ++ks) {
            const int g = (ks * 4 + quad) ^ (l15 & 7);
            const bf16x8 A2l = *reinterpret_cast<const bf16x8*>(&h1w[l15 * 64 + g * 8]);
            p0 = __builtin_amdgcn_mfma_f32_16x16x32_bf16(A2l, W2f[ks][0], p0, 0, 0, 0);
            p1 = __builtin_amdgcn_mfma_f32_16x16x32_bf16(A2l, W2f[ks][1], p1, 0, 0, 0);
        }
        // layer 3: relu + dot(W3), reduce across the 16 lanes of each quad
        float sv[4];
        #pragma unroll
        for (int r = 0; r < 4; ++r)
            sv[r] = fmaxf(p0[r] + b2a, 0.f) * w3a + fmaxf(p1[r] + b2b, 0.f) * w3b;
        #pragma unroll
        for (int off = 1; off < 16; off <<= 1) {
            #pragma unroll
            for (int r = 0; r < 4; ++r) sv[r] += __shfl_xor(sv[r], off);
        }
        if (l15 == 0) {
            #pragma unroll
            for (int r = 0; r < 4; ++r) sm.w[wave][t0 + quad * 4 + r] = sv[r];  // raw
        }
    }

    // ---- per-wave masked softmax over t (shuffle-based, no barrier) ----
    {
        const float NINF = -__builtin_inff();
        float v[4];
        #pragma unroll
        for (int i = 0; i < 4; ++i) {
            const int t = lane + i * 64;
            float x = NINF;
            if (t < 200) {
                const float raw = sm.w[wave][t];
                x = (kid[b * 200 + t] != 0) ? (raw + b3v) : NEG_INF_F;
            }
            v[i] = x;
        }
        float m = fmaxf(fmaxf(v[0], v[1]), fmaxf(v[2], v[3]));
        #pragma unroll
        for (int off = 1; off < 64; off <<= 1) m = fmaxf(m, __shfl_xor(m, off));
        float e[4], S = 0.f;
        #pragma unroll
        for (int i = 0; i < 4; ++i) { e[i] = __expf(v[i] - m); S += e[i]; }
        #pragma unroll
        for (int off = 1; off < 64; off <<= 1) S += __shfl_xor(S, off);
        const float inv = 1.0f / (S * 200.0f);   // normalize + mean(/T)
        #pragma unroll
        for (int i = 0; i < 4; ++i) {
            const int t = lane + i * 64;
            if (t < 208) sm.w[wave][t] = e[i] * inv;   // pad t: e==0
        }
    }

    // ---- pool: out[e] = sum_t w[t] * K[t][e], fp32 K re-read (L3-hot) ----
    {
        const int e2 = lane * 2;
        const float* kp = kbase + e2;
        float ax0 = 0.f, ay0 = 0.f, ax1 = 0.f, ay1 = 0.f;
        float ax2 = 0.f, ay2 = 0.f, ax3 = 0.f, ay3 = 0.f;
        #pragma unroll 5
        for (int t = 0; t < 200; t += 4) {
            const float4 wv = *reinterpret_cast<const float4*>(&sm.w[wave][t]); // broadcast
            const float2 x0 = *reinterpret_cast<const float2*>(kp + (t + 0) * 128);
            const float2 x1 = *reinterpret_cast<const float2*>(kp + (t + 1) * 128);
            const float2 x2 = *reinterpret_cast<const float2*>(kp + (t + 2) * 128);
            const float2 x3 = *reinterpret_cast<const float2*>(kp + (t + 3) * 128);
            ax0 += wv.x * x0.x; ay0 += wv.x * x0.y;
            ax1 += wv.y * x1.x; ay1 += wv.y * x1.y;
            ax2 += wv.z * x2.x; ay2 += wv.z * x2.y;
            ax3 += wv.w * x3.x; ay3 += wv.w * x3.y;
        }
        float2 o;
        o.x = (ax0 + ax1) + (ax2 + ax3);
        o.y = (ay0 + ay1) + (ay2 + ay3);
        *reinterpret_cast<float2*>(&out[(size_t)b * 128 + e2]) = o;
    }
}

extern "C" void kernel_launch(void* const* d_in, const int* in_sizes, int n_in,
                              void* d_out, int out_size, void* d_ws, size_t ws_size,
                              hipStream_t stream) {
    (void)in_sizes; (void)n_in; (void)out_size; (void)d_ws; (void)ws_size;
    attn_fused<<<dim3(512), dim3(256), 0, stream>>>(
        (const float*)d_in[0], (const float*)d_in[1], (const int*)d_in[2],
        (const float*)d_in[3], (const float*)d_in[4], (const float*)d_in[5],
        (const float*)d_in[6], (const float*)d_in[7], (const float*)d_in[8],
        (float*)d_out);
}

// Round 6
// 325.716 us; speedup vs baseline: 1.1004x; 1.0646x over previous
//
#include <hip/hip_runtime.h>
#include <hip/hip_bf16.h>

#define NEG_INF_F (-4294967295.0f)  // -(2^32)+1, matches reference padding

typedef __attribute__((ext_vector_type(8))) short bf16x8;   // MFMA A/B frag (4 VGPRs)
typedef __attribute__((ext_vector_type(4))) float f32x4;    // MFMA C/D frag

__device__ __forceinline__ unsigned short f2bf(float x) {
    unsigned u = __float_as_uint(x);
    return (unsigned short)((u + 0x7fffu + ((u >> 16) & 1u)) >> 16);  // RNE
}
__device__ __forceinline__ unsigned f2bf2(float a, float b) {
    __hip_bfloat162 h2 = __float22bfloat162_rn(make_float2(a, b));
    unsigned r; __builtin_memcpy(&r, &h2, 4); return r;
}
union FragU { unsigned u[4]; bf16x8 h; };

// One-pass design: K streamed HBM->regs once; online softmax fuses pool into
// the score loop. LDS ~28 KB; VGPR ~135 -> ~3 blocks/CU, 12 waves/CU.
struct __align__(16) Smem {
    unsigned short Mt[64 * 128];    // 16384 B  M^T bf16 [n][k], swizzle g=(k>>3)^(n&15)
    unsigned short h1s[4][16 * 64]; //  8192 B  per-wave h1 C->A scratch
    float q[128];                   //   512 B
    float cpart[256];               //  1024 B  4 partial chunks of c[n]
    float Om[4][128];               //  2048 B  per-wave pooled partials
    float mw[4], lw[4];             //    32 B  per-wave online-softmax state
};

// 2nd __launch_bounds__ arg = min BLOCKS/CU on this toolchain (R3 evidence):
// (256,3) -> 12 waves/CU -> VGPR cap 170; est. live ~135, no spill.
__global__ __launch_bounds__(256, 3)
void attn_fused(const float* __restrict__ Q,    // [2048,128]
                const float* __restrict__ Kg,   // [2048,200,128]
                const int*   __restrict__ kid,  // [2048,200]
                const float* __restrict__ W1,   // [512,64]
                const float* __restrict__ b1,   // [64]
                const float* __restrict__ W2,   // [64,32]
                const float* __restrict__ b2,   // [32]
                const float* __restrict__ W3,   // [32,1]
                const float* __restrict__ b3,   // [1]
                float* __restrict__ out)        // [2048,128]
{
    __shared__ Smem sm;
    const int b    = blockIdx.x;
    const int tid  = threadIdx.x;
    const int wave = tid >> 6;
    const int lane = tid & 63;
    const int l15  = lane & 15;
    const int quad = lane >> 4;

    if (tid < 128) sm.q[tid] = Q[b * 128 + tid];

    // W2 B-frags + layer-3 consts (global L2-hot, no LDS dependency)
    bf16x8 W2f[2][2];
    #pragma unroll
    for (int ks = 0; ks < 2; ++ks) {
        #pragma unroll
        for (int nt = 0; nt < 2; ++nt) {
            const int n = nt * 16 + l15;
            const int kb = ks * 32 + quad * 8;
            bf16x8 f;
            #pragma unroll
            for (int j = 0; j < 8; ++j) f[j] = (short)f2bf(W2[(kb + j) * 32 + n]);
            W2f[ks][nt] = f;
        }
    }
    const float w3a = W3[l15],  w3b = W3[16 + l15];
    const float b2a = b2[l15],  b2b = b2[16 + l15];
    const float b3v = b3[0];
    __syncthreads();

    // ---- cooperative M build: M[k][n] = (W1k-W1d)[k][n] + q[k]*W1p[k][n] ----
    // stored transposed Mt[n][k], bf16, granule swizzle g=(k>>3)^(n&15).
    {
        const int n  = tid & 63;
        const int ko = (tid >> 6) * 2;
        #pragma unroll
        for (int i = 0; i < 16; ++i) {
            const int k = i * 8 + ko;
            const float v0 = (W1[(128 + k) * 64 + n] - W1[(256 + k) * 64 + n])
                           + sm.q[k] * W1[(384 + k) * 64 + n];
            const float v1 = (W1[(129 + k) * 64 + n] - W1[(257 + k) * 64 + n])
                           + sm.q[k + 1] * W1[(385 + k) * 64 + n];
            const int g = (k >> 3) ^ (n & 15);
            *reinterpret_cast<unsigned*>(&sm.Mt[n * 128 + g * 8 + (k & 7)]) = f2bf2(v0, v1);
        }
    }
    // c[n] partials: wave w does 32 k's
    {
        const int n = tid & 63, kc = tid >> 6;
        float acc = (kc == 0) ? b1[n] : 0.0f;
        #pragma unroll 4
        for (int i = 0; i < 32; ++i) {
            const int k = kc * 32 + i;
            acc += sm.q[k] * (W1[k * 64 + n] + W1[(256 + k) * 64 + n]);
        }
        sm.cpart[kc * 64 + n] = acc;
    }
    __syncthreads();

    float cn[4];
    #pragma unroll
    for (int nt = 0; nt < 4; ++nt) {
        const int n = nt * 16 + l15;
        cn[nt] = sm.cpart[n] + sm.cpart[64 + n] + sm.cpart[128 + n] + sm.cpart[192 + n];
    }

    const float* kbase = Kg + (size_t)b * 25600;
    unsigned short* h1w = &sm.h1s[wave][0];
    const f32x4 zero4 = {0.f, 0.f, 0.f, 0.f};

    float O[32];
    #pragma unroll
    for (int i = 0; i < 32; ++i) O[i] = 0.0f;
    float mrun = -__builtin_inff(), lrun = 0.0f;

    // ---- tile loop: wave w does tiles w, w+4, w+8 (w==0 also 12) ----
    for (int tile = wave; tile < 13; tile += 4) {
        const int t0 = tile * 16;
        const int t  = t0 + l15;
        const int tr = min(t, 199);               // clamp OOB rows (tile 12)
        const float* kr = kbase + tr * 128;
        float4 ka[4], kb_[4];
        #pragma unroll
        for (int ks = 0; ks < 4; ++ks) {
            ka[ks]  = *reinterpret_cast<const float4*>(kr + ks * 32 + quad * 8);
            kb_[ks] = *reinterpret_cast<const float4*>(kr + ks * 32 + quad * 8 + 4);
        }
        const int kidv = kid[b * 200 + tr];

        f32x4 acc[4] = {zero4, zero4, zero4, zero4};
        #pragma unroll
        for (int ks = 0; ks < 4; ++ks) {
            FragU A;
            A.u[0] = f2bf2(ka[ks].x,  ka[ks].y);
            A.u[1] = f2bf2(ka[ks].z,  ka[ks].w);
            A.u[2] = f2bf2(kb_[ks].x, kb_[ks].y);
            A.u[3] = f2bf2(kb_[ks].z, kb_[ks].w);
            #pragma unroll
            for (int nt = 0; nt < 4; ++nt) {
                const int n = nt * 16 + l15;
                const int g = (ks * 4 + quad) ^ l15;
                const bf16x8 Bf = *reinterpret_cast<const bf16x8*>(&sm.Mt[n * 128 + g * 8]);
                acc[nt] = __builtin_amdgcn_mfma_f32_16x16x32_bf16(A.h, Bf, acc[nt], 0, 0, 0);
            }
        }
        // epilogue: + c[n], relu, bf16 -> wave-private scratch in A-layout
        #pragma unroll
        for (int nt = 0; nt < 4; ++nt) {
            const int n = nt * 16 + l15;
            #pragma unroll
            for (int r = 0; r < 4; ++r) {
                const int m = quad * 4 + r;
                const float h = fmaxf(acc[nt][r] + cn[nt], 0.0f);
                const int g = (n >> 3) ^ (m & 7);
                h1w[m * 64 + g * 8 + (n & 7)] = f2bf(h);
            }
        }
        // layer 2: [16,64] @ [64,32]
        f32x4 p0 = zero4, p1 = zero4;
        #pragma unroll
        for (int ks = 0; ks < 2; ++ks) {
            const int g = (ks * 4 + quad) ^ (l15 & 7);
            const bf16x8 A2l = *reinterpret_cast<const bf16x8*>(&h1w[l15 * 64 + g * 8]);
            p0 = __builtin_amdgcn_mfma_f32_16x16x32_bf16(A2l, W2f[ks][0], p0, 0, 0, 0);
            p1 = __builtin_amdgcn_mfma_f32_16x16x32_bf16(A2l, W2f[ks][1], p1, 0, 0, 0);
        }
        // layer 3: relu + dot(W3), reduce over the 16 cols (l15)
        float sv[4];
        #pragma unroll
        for (int r = 0; r < 4; ++r)
            sv[r] = fmaxf(p0[r] + b2a, 0.f) * w3a + fmaxf(p1[r] + b2b, 0.f) * w3b;
        #pragma unroll
        for (int off = 1; off < 16; off <<= 1) {
            #pragma unroll
            for (int r = 0; r < 4; ++r) sv[r] += __shfl_xor(sv[r], off);
        }
        // broadcast: this lane needs score of t0+l15 (lives in quad l15>>2, reg l15&3)
        const int src = (l15 >> 2) * 16;
        const float s0 = __shfl(sv[0], src), s1 = __shfl(sv[1], src);
        const float s2 = __shfl(sv[2], src), s3 = __shfl(sv[3], src);
        const int rr = l15 & 3;
        const float sres = (rr == 0) ? s0 : (rr == 1) ? s1 : (rr == 2) ? s2 : s3;
        float x;
        if (t < 200) x = (kidv != 0) ? (sres + b3v) : NEG_INF_F;
        else         x = -__builtin_inff();
        // online softmax update (all cross-lane ops within 16-lane groups)
        float tmax = x;
        #pragma unroll
        for (int off = 1; off < 16; off <<= 1) tmax = fmaxf(tmax, __shfl_xor(tmax, off));
        const float mnew  = fmaxf(mrun, tmax);
        const float alpha = __expf(mrun - mnew);
        const float w     = __expf(x - mnew);
        float tsum = w;
        #pragma unroll
        for (int off = 1; off < 16; off <<= 1) tsum += __shfl_xor(tsum, off);
        lrun = lrun * alpha + tsum;
        mrun = mnew;
        #pragma unroll
        for (int ks = 0; ks < 4; ++ks) {
            O[ks*8+0] = fmaf(O[ks*8+0], alpha, w * ka[ks].x);
            O[ks*8+1] = fmaf(O[ks*8+1], alpha, w * ka[ks].y);
            O[ks*8+2] = fmaf(O[ks*8+2], alpha, w * ka[ks].z);
            O[ks*8+3] = fmaf(O[ks*8+3], alpha, w * ka[ks].w);
            O[ks*8+4] = fmaf(O[ks*8+4], alpha, w * kb_[ks].x);
            O[ks*8+5] = fmaf(O[ks*8+5], alpha, w * kb_[ks].y);
            O[ks*8+6] = fmaf(O[ks*8+6], alpha, w * kb_[ks].z);
            O[ks*8+7] = fmaf(O[ks*8+7], alpha, w * kb_[ks].w);
        }
    }

    // intra-wave reduce of O over l15 (each quad owns cols quad*8+ks*32..+7)
    #pragma unroll
    for (int off = 1; off < 16; off <<= 1) {
        #pragma unroll
        for (int i = 0; i < 32; ++i) O[i] += __shfl_xor(O[i], off);
    }
    if (l15 == 0) {
        #pragma unroll
        for (int ks = 0; ks < 4; ++ks) {
            *reinterpret_cast<float4*>(&sm.Om[wave][ks * 32 + quad * 8]) =
                make_float4(O[ks*8+0], O[ks*8+1], O[ks*8+2], O[ks*8+3]);
            *reinterpret_cast<float4*>(&sm.Om[wave][ks * 32 + quad * 8 + 4]) =
                make_float4(O[ks*8+4], O[ks*8+5], O[ks*8+6], O[ks*8+7]);
        }
    }
    if (lane == 0) { sm.mw[wave] = mrun; sm.lw[wave] = lrun; }
    __syncthreads();

    // ---- merge 4 waves' online states, normalize, store ----
    if (tid < 128) {
        const float M = fmaxf(fmaxf(sm.mw[0], sm.mw[1]), fmaxf(sm.mw[2], sm.mw[3]));
        float den = 0.f, val = 0.f;
        #pragma unroll
        for (int w = 0; w < 4; ++w) {
            const float a = __expf(sm.mw[w] - M);
            den += sm.lw[w] * a;
            val += sm.Om[w][tid] * a;
        }
        out[(size_t)b * 128 + tid] = val / (den * 200.0f);  // softmax norm + mean(/T)
    }
}

extern "C" void kernel_launch(void* const* d_in, const int* in_sizes, int n_in,
                              void* d_out, int out_size, void* d_ws, size_t ws_size,
                              hipStream_t stream) {
    (void)in_sizes; (void)n_in; (void)out_size; (void)d_ws; (void)ws_size;
    attn_fused<<<dim3(2048), dim3(256), 0, stream>>>(
        (const float*)d_in[0], (const float*)d_in[1], (const int*)d_in[2],
        (const float*)d_in[3], (const float*)d_in[4], (const float*)d_in[5],
        (const float*)d_in[6], (const float*)d_in[7], (const float*)d_in[8],
        (float*)d_out);
}